// Round 5
// baseline (1064.903 us; speedup 1.0000x reference)
//
#include <hip/hip_runtime.h>
#include <hip/hip_bf16.h>
#include <cstdint>

// HopfieldLayer: out = attn(attn(R,Y,Y), Y, Y), H=8 heads, E=64, scale 1/8.
// R5: bisect of R4. KEEP: QK^T A-frags loaded per-lane from global (L2-resident,
// -8 ds_read_b128/wave-tile) and V-tile staged to LDS from those registers
// (-4 global staging loads). REVERT to R3-proven: P^T redistribution via
// wave-local LDS (Plds) and shfl_xor max-reduce (the R4 permlane paths are the
// prime correctness suspects).

typedef __attribute__((ext_vector_type(8))) short bf16x8;
typedef __attribute__((ext_vector_type(4))) short short4v;
typedef __attribute__((ext_vector_type(4))) float f32x4;

constexpr int B_ = 2, L_ = 2048, S_ = 2048, H_ = 8, E_ = 64, DM_ = 512;
constexpr int NTH_ = 16; // KV tiles per S-half (32 total / 2)
constexpr float SCALE2 = 0.18033688011112042f; // (1/sqrt(64)) * log2(e)

__device__ __forceinline__ ushort f2bf(float a) {
  uint32_t u = __builtin_bit_cast(uint32_t, a);
  return (ushort)((u + 0x7fffu + ((u >> 16) & 1u)) >> 16); // RNE, finite inputs
}
__device__ __forceinline__ uint32_t bf16pack(float a, float b) {
  uint32_t ua = __builtin_bit_cast(uint32_t, a);
  uint32_t ub = __builtin_bit_cast(uint32_t, b);
  ua = (ua + 0x7fffu + ((ua >> 16) & 1u)) >> 16;
  ub = (ub + 0x7fffu + ((ub >> 16) & 1u)) >> 16;
  return (ua & 0xffffu) | (ub << 16);
}

__global__ void cvt_kernel(const float* __restrict__ in, ushort* __restrict__ out,
                           int n4, float mul) {
  int i = blockIdx.x * 256 + threadIdx.x;
  if (i >= n4) return;
  float4 v = reinterpret_cast<const float4*>(in)[i];
  ushort4 o;
  o.x = f2bf(v.x * mul); o.y = f2bf(v.y * mul);
  o.z = f2bf(v.z * mul); o.w = f2bf(v.w * mul);
  reinterpret_cast<ushort4*>(out)[i] = o;
}

// V LDS tile: 64s x 64e bf16, sub-tiled for tr-reads:
//   idx(s,e) = block*64 + (s&3)*16 + (e&15),
//   block = (((s>>2)&1)*4 + (e>>4))*8 + (s>>3)
// P LDS (per wave, 512 u32): u32 idx = ((nt*16+qi)*4+g)*2+w
template <bool OUT_F32>
__global__ __launch_bounds__(256, 4) void attn_kernel(
    const ushort* __restrict__ Qb,  // bf16 [B,L,512], pre-scaled by SCALE2
    const ushort* __restrict__ Yb,  // bf16 [B,S,512]
    float* __restrict__ outF, ushort* __restrict__ outB) {
  __shared__ ushort Vsub[2][2][4096]; // [s-half pair][double-buf] 32 KB
  __shared__ uint32_t Plds[4][512];   // 8 KB, wave-private P^T staging

  const int tid = threadIdx.x;
  const int lane = tid & 63;
  const int wid = tid >> 6;
  const int g = lane >> 4;   // 16-lane group 0..3
  const int qi = lane & 15;  // this lane's q column
  const int pair = wid >> 1; // S-half this wave works on
  const int qs = wid & 1;    // q sub-tile (16 rows) within the wg's 32

  const int wg = blockIdx.x;
  const int qt = wg & 63;         // L/32 = 64 q-tiles
  const int h = (wg >> 6) & 7;
  const int b = wg >> 9;

  const int qglob = qt * 32 + qs * 16 + qi;
  const size_t qrow_off = (size_t)(b * L_ + qglob) * DM_ + h * E_;

  // Q B-fragments (lane holds Q[qi][8 contiguous e])
  bf16x8 qf0 = *reinterpret_cast<const bf16x8*>(Qb + qrow_off + g * 8);
  bf16x8 qf1 = *reinterpret_cast<const bf16x8*>(Qb + qrow_off + 32 + g * 8);

  f32x4 oacc[4];
#pragma unroll
  for (int et = 0; et < 4; ++et) oacc[et] = f32x4{0.f, 0.f, 0.f, 0.f};
  float m = -1e30f, lsum = 0.f;

  const int ybase = b * S_ * DM_ + h * E_;

  // K-frag global element offsets, frag i = nt*2+eck:
  // K[s = pair*1024 + nt*16 + qi][e = eck*32 + 8g .. +8]
  int koff[8];
#pragma unroll
  for (int nt = 0; nt < 4; ++nt)
#pragma unroll
    for (int eck = 0; eck < 2; ++eck)
      koff[nt * 2 + eck] =
          ybase + (pair * 1024 + nt * 16 + qi) * DM_ + eck * 32 + 8 * g;

  // V-write LDS element offsets for this wave's eck==qs frags
  int widx[4];
#pragma unroll
  for (int nt = 0; nt < 4; ++nt) {
    int s = nt * 16 + qi, e0 = qs * 32 + 8 * g;
    widx[nt] = ((((s >> 2) & 1) * 4 + (e0 >> 4)) * 8 + (s >> 3)) * 64 +
               (s & 3) * 16 + (e0 & 15);
  }

  // ---- prologue: load frags(0); stage V tile 0 into buffer 0
  bf16x8 fr[8];
#pragma unroll
  for (int i = 0; i < 8; ++i)
    fr[i] = *reinterpret_cast<const bf16x8*>(Yb + koff[i]);
#pragma unroll
  for (int nt = 0; nt < 4; ++nt)
    *reinterpret_cast<bf16x8*>(&Vsub[pair][0][widx[nt]]) = fr[nt * 2 + qs];
  __syncthreads();

  const uint32_t vb0 = (uint32_t)(uintptr_t)(&Vsub[pair][0][0]);
  int cur = 0;

  for (int t = 0; t < NTH_; ++t) {
    const uint32_t vbc = vb0 + (uint32_t)(cur * 8192);

    // ---- S^T = mfma(A=K frags, B=Q): D[s-in-16][q], row=4g+reg, col=qi
    f32x4 st[4];
#pragma unroll
    for (int nt = 0; nt < 4; ++nt) {
      f32x4 acc = f32x4{0.f, 0.f, 0.f, 0.f};
      acc = __builtin_amdgcn_mfma_f32_16x16x32_bf16(fr[nt * 2 + 0], qf0, acc, 0, 0, 0);
      acc = __builtin_amdgcn_mfma_f32_16x16x32_bf16(fr[nt * 2 + 1], qf1, acc, 0, 0, 0);
      st[nt] = acc;
    }

    // ---- issue next tile's K-frag loads (hide under softmax+PV)
    const int tadd = ((t + 1 < NTH_) ? t + 1 : t) * 64 * DM_;
#pragma unroll
    for (int i = 0; i < 8; ++i)
      fr[i] = *reinterpret_cast<const bf16x8*>(Yb + koff[i] + tadd);

    // ---- online softmax with defer-max (T13, THR=8); exp2 domain
    float tm = -1e30f;
#pragma unroll
    for (int nt = 0; nt < 4; ++nt)
#pragma unroll
      for (int r = 0; r < 4; ++r) tm = fmaxf(tm, st[nt][r]);
    tm = fmaxf(tm, __shfl_xor(tm, 16));
    tm = fmaxf(tm, __shfl_xor(tm, 32));
    if (__any(tm > m + 8.f)) {
      float mnew = fmaxf(m, tm);
      float alpha = __builtin_amdgcn_exp2f(m - mnew);
      m = mnew;
      lsum *= alpha;
#pragma unroll
      for (int et = 0; et < 4; ++et) oacc[et] *= alpha;
    }
    float p[16];
#pragma unroll
    for (int i = 0; i < 16; ++i) {
      p[i] = __builtin_amdgcn_exp2f(st[i >> 2][i & 3] - m); // bounded by 2^8
      lsum += p[i];
    }

    // ---- P^T to wave-local LDS: [nt][qi][g][w]
#pragma unroll
    for (int nt = 0; nt < 4; ++nt) {
      uint2 w;
      w.x = bf16pack(p[nt * 4 + 0], p[nt * 4 + 1]);
      w.y = bf16pack(p[nt * 4 + 2], p[nt * 4 + 3]);
      *reinterpret_cast<uint2*>(&Plds[wid][((nt * 16 + qi) * 4 + g) * 2]) = w;
    }

    // ---- PV: O^T[e][q] += mfma(A=V^T tr-reads, B=P^T) over 2 k-chunks
#pragma unroll
    for (int ck = 0; ck < 2; ++ck) {
      uint4 pw = *reinterpret_cast<const uint4*>(
          &Plds[wid][(((2 * ck + (g >> 1)) * 16 + qi) * 4 + 2 * (g & 1)) * 2]);
      bf16x8 pfrag = __builtin_bit_cast(bf16x8, pw);

      short4v tr[4][2];
#pragma unroll
      for (int et = 0; et < 4; ++et)
#pragma unroll
        for (int pb = 0; pb < 2; ++pb) {
          uint32_t addr = vbc + (uint32_t)((((pb * 4 + et) * 8) + 4 * ck) * 128) + 8u * (uint32_t)lane;
          asm volatile("ds_read_b64_tr_b16 %0, %1" : "=v"(tr[et][pb]) : "v"(addr));
        }
      asm volatile("s_waitcnt lgkmcnt(0)" ::: "memory");
      __builtin_amdgcn_sched_barrier(0); // rule #18

#pragma unroll
      for (int et = 0; et < 4; ++et) {
        short4v lo = tr[et][0], hi = tr[et][1];
        bf16x8 vf;
        vf[0] = lo[0]; vf[1] = lo[1]; vf[2] = lo[2]; vf[3] = lo[3];
        vf[4] = hi[0]; vf[5] = hi[1]; vf[6] = hi[2]; vf[7] = hi[3];
        oacc[et] = __builtin_amdgcn_mfma_f32_16x16x32_bf16(vf, pfrag, oacc[et], 0, 0, 0);
      }
    }

    // ---- stage next V tile from the freshly-loaded frags; one barrier/tile
    if (t + 1 < NTH_) {
#pragma unroll
      for (int nt = 0; nt < 4; ++nt)
        *reinterpret_cast<bf16x8*>(&Vsub[pair][cur ^ 1][widx[nt]]) = fr[nt * 2 + qs];
      __syncthreads();
      cur ^= 1;
    }
  }

  // ---- per-wave l reduction (across g for each qi)
  lsum += __shfl_xor(lsum, 16);
  lsum += __shfl_xor(lsum, 32);

  // ---- merge the two S-halves (wave w in {0,1} with wave w+2) via LDS
  __syncthreads(); // all KV reads done; Vsub reusable as merge scratch
  float* mrgO = (float*)&Vsub[0][0][0];   // [pw][et][lane][4] = 2048 f32
  float* mrgML = mrgO + 2048;             // [pw][{m,l}][lane] = 256 f32

  if (wid >= 2) {
    const int pw = wid - 2;
#pragma unroll
    for (int et = 0; et < 4; ++et)
      *reinterpret_cast<f32x4*>(&mrgO[((pw * 4 + et) * 64 + lane) * 4]) = oacc[et];
    mrgML[pw * 128 + lane] = m;
    mrgML[pw * 128 + 64 + lane] = lsum;
  }
  __syncthreads();
  if (wid < 2) {
    const int pw = wid;
    float m1 = mrgML[pw * 128 + lane];
    float l1 = mrgML[pw * 128 + 64 + lane];
    float M = fmaxf(m, m1);
    float f0 = __builtin_amdgcn_exp2f(m - M);
    float f1 = __builtin_amdgcn_exp2f(m1 - M);
    float inv = 1.0f / (lsum * f0 + l1 * f1);
#pragma unroll
    for (int et = 0; et < 4; ++et) {
      f32x4 O1 = *reinterpret_cast<const f32x4*>(&mrgO[((pw * 4 + et) * 64 + lane) * 4]);
#pragma unroll
      for (int r = 0; r < 4; ++r) {
        int e = et * 16 + 4 * g + r;
        float val = (oacc[et][r] * f0 + O1[r] * f1) * inv;
        if constexpr (OUT_F32) outF[qrow_off + e] = val;
        else outB[qrow_off + e] = f2bf(val * SCALE2); // pre-scale for step-2 Q
      }
    }
  }
}

extern "C" void kernel_launch(void* const* d_in, const int* in_sizes, int n_in,
                              void* d_out, int out_size, void* d_ws, size_t ws_size,
                              hipStream_t stream) {
  const float* R = (const float*)d_in[0];
  const float* Y = (const float*)d_in[1];
  float* outF = (float*)d_out;

  constexpr int NE = B_ * L_ * DM_; // 2,097,152 elements per tensor
  ushort* Rb = (ushort*)d_ws;
  ushort* Yb = Rb + NE;
  ushort* q1 = Yb + NE;

  const int n4 = NE / 4;
  cvt_kernel<<<dim3((n4 + 255) / 256), 256, 0, stream>>>(R, Rb, n4, SCALE2);
  cvt_kernel<<<dim3((n4 + 255) / 256), 256, 0, stream>>>(Y, Yb, n4, 1.0f);

  const int ngrid = B_ * H_ * (L_ / 32); // 1024 workgroups = 4 blocks/CU
  attn_kernel<false><<<dim3(ngrid), 256, 0, stream>>>(Rb, Yb, nullptr, q1);
  attn_kernel<true><<<dim3(ngrid), 256, 0, stream>>>(q1, Yb, outF, nullptr);
}

// Round 6
// 86.699 us; speedup vs baseline: 12.2828x; 12.2828x over previous
//
#include <hip/hip_runtime.h>
#include <hip/hip_bf16.h>
#include <cstdint>

// HopfieldLayer: out = attn(attn(R,Y,Y), Y, Y), H=8 heads, E=64, scale 1/8.
// R6: revert R5's K-gather (catastrophic: uncoalesced 16-line VMEM). Base = R3.
// New: each wave owns 32 q-rows (2 Q B-frag sets) so every K ds_read_b128 and
// every V^T tr-read feeds 2 MFMAs -> per-CU LDS traffic cut 1.71x. Grid 512,
// wg = 64 q x 2 S-halves (2-way merge, R3-proven). launch_bounds(256,2).

typedef __attribute__((ext_vector_type(8))) short bf16x8;
typedef __attribute__((ext_vector_type(4))) short short4v;
typedef __attribute__((ext_vector_type(4))) float f32x4;

constexpr int B_ = 2, L_ = 2048, S_ = 2048, H_ = 8, E_ = 64, DM_ = 512;
constexpr int NTH_ = 16; // KV tiles per S-half (32 total / 2)
constexpr float SCALE2 = 0.18033688011112042f; // (1/sqrt(64)) * log2(e)

__device__ __forceinline__ ushort f2bf(float a) {
  uint32_t u = __builtin_bit_cast(uint32_t, a);
  return (ushort)((u + 0x7fffu + ((u >> 16) & 1u)) >> 16); // RNE, finite inputs
}
__device__ __forceinline__ uint32_t bf16pack(float a, float b) {
  uint32_t ua = __builtin_bit_cast(uint32_t, a);
  uint32_t ub = __builtin_bit_cast(uint32_t, b);
  ua = (ua + 0x7fffu + ((ua >> 16) & 1u)) >> 16;
  ub = (ub + 0x7fffu + ((ub >> 16) & 1u)) >> 16;
  return (ua & 0xffffu) | (ub << 16);
}

__global__ void cvt_kernel(const float* __restrict__ in, ushort* __restrict__ out,
                           int n4, float mul) {
  int i = blockIdx.x * 256 + threadIdx.x;
  if (i >= n4) return;
  float4 v = reinterpret_cast<const float4*>(in)[i];
  ushort4 o;
  o.x = f2bf(v.x * mul); o.y = f2bf(v.y * mul);
  o.z = f2bf(v.z * mul); o.w = f2bf(v.w * mul);
  reinterpret_cast<ushort4*>(out)[i] = o;
}

// KV LDS tile: 64s x 64e bf16, sub-tiled for tr-reads:
//   idx(s,e) = block*64 + (s&3)*16 + (e&15),
//   block = (((s>>2)&1)*4 + (e>>4))*8 + (s>>3)
// P LDS (per wave, per q-set, 512 u32): u32 idx = ((nt*16+qi)*4+g)*2+w
template <bool OUT_F32>
__global__ __launch_bounds__(256, 2) void attn_kernel(
    const ushort* __restrict__ Qb,  // bf16 [B,L,512], pre-scaled by SCALE2
    const ushort* __restrict__ Yb,  // bf16 [B,S,512]
    float* __restrict__ outF, ushort* __restrict__ outB) {
  __shared__ ushort Vsub[2][2][4096];   // [s-half pair][double-buf] 32 KB
  __shared__ uint32_t Plds[4][2][512];  // [wave][q-set] 16 KB

  const int tid = threadIdx.x;
  const int lane = tid & 63;
  const int wid = tid >> 6;
  const int g = lane >> 4;   // 16-lane group 0..3
  const int qi = lane & 15;  // this lane's q column
  const int pair = wid >> 1; // S-half this wave works on
  const int qs = wid & 1;    // 32-row q sub-tile within the wg's 64

  const int wg = blockIdx.x;
  const int qt = wg & 31;         // L/64 = 32 q-tiles
  const int h = (wg >> 5) & 7;
  const int b = wg >> 8;

  const size_t qrow0 = (size_t)(b * L_ + qt * 64 + qs * 32 + qi) * DM_ + h * E_;
  const size_t qrow1 = qrow0 + 16 * DM_;

  // Q B-fragments, 2 sets x 2 e-chunks (lane holds Q[q][8 contiguous e])
  bf16x8 qfL0 = *reinterpret_cast<const bf16x8*>(Qb + qrow0 + g * 8);
  bf16x8 qfL1 = *reinterpret_cast<const bf16x8*>(Qb + qrow0 + 32 + g * 8);
  bf16x8 qfH0 = *reinterpret_cast<const bf16x8*>(Qb + qrow1 + g * 8);
  bf16x8 qfH1 = *reinterpret_cast<const bf16x8*>(Qb + qrow1 + 32 + g * 8);

  f32x4 oaccL[4], oaccH[4];
#pragma unroll
  for (int et = 0; et < 4; ++et) {
    oaccL[et] = f32x4{0.f, 0.f, 0.f, 0.f};
    oaccH[et] = f32x4{0.f, 0.f, 0.f, 0.f};
  }
  float mL = -1e30f, lsumL = 0.f, mH = -1e30f, lsumH = 0.f;

  const size_t ybase = (size_t)(b * S_) * DM_ + h * E_;

  // staging geometry: wave-pair (128 threads) stages its own 8 KB tile
  const int ptid = tid & 127;
  const int cc = ptid & 7;              // e-chunk (8 bf16)
  int lidx[4];
  const ushort* gsrc[4];
#pragma unroll
  for (int it = 0; it < 4; ++it) {
    int r = it * 16 + (ptid >> 3);      // s-row 0..63
    lidx[it] = ((((r >> 2) & 1) * 4 + (cc >> 1)) * 8 + (r >> 3)) * 64 +
               (r & 3) * 16 + (cc & 1) * 8;
    gsrc[it] = Yb + ybase + (size_t)(pair * 1024 + r) * DM_ + cc * 8;
  }

  // ---- prologue: stage tile 0 of this S-half into buffer 0
#pragma unroll
  for (int it = 0; it < 4; ++it)
    *reinterpret_cast<uint4*>(&Vsub[pair][0][lidx[it]]) =
        *reinterpret_cast<const uint4*>(gsrc[it]);
  __syncthreads();

  const uint32_t vb0 = (uint32_t)(uintptr_t)(&Vsub[pair][0][0]);
  int cur = 0;

  for (int t = 0; t < NTH_; ++t) {
    // ---- issue next tile's global loads early
    const int tn = (t + 1 < NTH_) ? t + 1 : t;
    uint4 pf[4];
#pragma unroll
    for (int it = 0; it < 4; ++it)
      pf[it] = *reinterpret_cast<const uint4*>(gsrc[it] + (size_t)tn * 64 * DM_);

    const ushort* Vc = &Vsub[pair][cur][0];
    const uint32_t vbc = vb0 + (uint32_t)(cur * 8192);

    // ---- S^T = mfma(A=K, B=Q): each K A-frag read feeds BOTH q-sets
    f32x4 stL[4], stH[4];
#pragma unroll
    for (int nt = 0; nt < 4; ++nt) {
      f32x4 aL = f32x4{0.f, 0.f, 0.f, 0.f};
      f32x4 aH = f32x4{0.f, 0.f, 0.f, 0.f};
#pragma unroll
      for (int eck = 0; eck < 2; ++eck) {
        int s = nt * 16 + qi;
        int idx = ((((s >> 2) & 1) * 4 + (eck * 2 + (g >> 1))) * 8 + (s >> 3)) * 64 +
                  (s & 3) * 16 + (g & 1) * 8;
        bf16x8 ak = *reinterpret_cast<const bf16x8*>(&Vc[idx]);
        aL = __builtin_amdgcn_mfma_f32_16x16x32_bf16(ak, eck ? qfL1 : qfL0, aL, 0, 0, 0);
        aH = __builtin_amdgcn_mfma_f32_16x16x32_bf16(ak, eck ? qfH1 : qfH0, aH, 0, 0, 0);
      }
      stL[nt] = aL;
      stH[nt] = aH;
    }

    // ---- online softmax + P-write, set L then set H (defer-max T13, THR=8)
    {
      float tm = -1e30f;
#pragma unroll
      for (int nt = 0; nt < 4; ++nt)
#pragma unroll
        for (int r = 0; r < 4; ++r) tm = fmaxf(tm, stL[nt][r]);
      tm = fmaxf(tm, __shfl_xor(tm, 16));
      tm = fmaxf(tm, __shfl_xor(tm, 32));
      if (__any(tm > mL + 8.f)) {
        float mnew = fmaxf(mL, tm);
        float alpha = __builtin_amdgcn_exp2f(mL - mnew);
        mL = mnew;
        lsumL *= alpha;
#pragma unroll
        for (int et = 0; et < 4; ++et) oaccL[et] *= alpha;
      }
#pragma unroll
      for (int nt = 0; nt < 4; ++nt) {
        float p0 = __builtin_amdgcn_exp2f(stL[nt][0] - mL);
        float p1 = __builtin_amdgcn_exp2f(stL[nt][1] - mL);
        float p2 = __builtin_amdgcn_exp2f(stL[nt][2] - mL);
        float p3 = __builtin_amdgcn_exp2f(stL[nt][3] - mL);
        lsumL += (p0 + p1) + (p2 + p3);
        uint2 w;
        w.x = bf16pack(p0, p1);
        w.y = bf16pack(p2, p3);
        *reinterpret_cast<uint2*>(&Plds[wid][0][((nt * 16 + qi) * 4 + g) * 2]) = w;
      }
    }
    {
      float tm = -1e30f;
#pragma unroll
      for (int nt = 0; nt < 4; ++nt)
#pragma unroll
        for (int r = 0; r < 4; ++r) tm = fmaxf(tm, stH[nt][r]);
      tm = fmaxf(tm, __shfl_xor(tm, 16));
      tm = fmaxf(tm, __shfl_xor(tm, 32));
      if (__any(tm > mH + 8.f)) {
        float mnew = fmaxf(mH, tm);
        float alpha = __builtin_amdgcn_exp2f(mH - mnew);
        mH = mnew;
        lsumH *= alpha;
#pragma unroll
        for (int et = 0; et < 4; ++et) oaccH[et] *= alpha;
      }
#pragma unroll
      for (int nt = 0; nt < 4; ++nt) {
        float p0 = __builtin_amdgcn_exp2f(stH[nt][0] - mH);
        float p1 = __builtin_amdgcn_exp2f(stH[nt][1] - mH);
        float p2 = __builtin_amdgcn_exp2f(stH[nt][2] - mH);
        float p3 = __builtin_amdgcn_exp2f(stH[nt][3] - mH);
        lsumH += (p0 + p1) + (p2 + p3);
        uint2 w;
        w.x = bf16pack(p0, p1);
        w.y = bf16pack(p2, p3);
        *reinterpret_cast<uint2*>(&Plds[wid][1][((nt * 16 + qi) * 4 + g) * 2]) = w;
      }
    }

    // ---- PV: each V^T tr-read frag feeds BOTH q-sets
#pragma unroll
    for (int ck = 0; ck < 2; ++ck) {
      const int pidx = (((2 * ck + (g >> 1)) * 16 + qi) * 4 + 2 * (g & 1)) * 2;
      uint4 pwL = *reinterpret_cast<const uint4*>(&Plds[wid][0][pidx]);
      uint4 pwH = *reinterpret_cast<const uint4*>(&Plds[wid][1][pidx]);
      bf16x8 pfragL = __builtin_bit_cast(bf16x8, pwL);
      bf16x8 pfragH = __builtin_bit_cast(bf16x8, pwH);

      short4v tr[4][2];
#pragma unroll
      for (int et = 0; et < 4; ++et)
#pragma unroll
        for (int pb = 0; pb < 2; ++pb) {
          uint32_t addr = vbc + (uint32_t)((((pb * 4 + et) * 8) + 4 * ck) * 128) + 8u * (uint32_t)lane;
          asm volatile("ds_read_b64_tr_b16 %0, %1" : "=v"(tr[et][pb]) : "v"(addr));
        }
      asm volatile("s_waitcnt lgkmcnt(0)" ::: "memory");
      __builtin_amdgcn_sched_barrier(0); // rule #18

#pragma unroll
      for (int et = 0; et < 4; ++et) {
        short4v lo = tr[et][0], hi = tr[et][1];
        bf16x8 vf;
        vf[0] = lo[0]; vf[1] = lo[1]; vf[2] = lo[2]; vf[3] = lo[3];
        vf[4] = hi[0]; vf[5] = hi[1]; vf[6] = hi[2]; vf[7] = hi[3];
        oaccL[et] = __builtin_amdgcn_mfma_f32_16x16x32_bf16(vf, pfragL, oaccL[et], 0, 0, 0);
        oaccH[et] = __builtin_amdgcn_mfma_f32_16x16x32_bf16(vf, pfragH, oaccH[et], 0, 0, 0);
      }
    }

    // ---- write next tile into the other buffer; single barrier per tile
    if (t + 1 < NTH_) {
#pragma unroll
      for (int it = 0; it < 4; ++it)
        *reinterpret_cast<uint4*>(&Vsub[pair][cur ^ 1][lidx[it]]) = pf[it];
      __syncthreads();
      cur ^= 1;
    }
  }

  // ---- per-wave l reductions (across g for each qi)
  lsumL += __shfl_xor(lsumL, 16);
  lsumL += __shfl_xor(lsumL, 32);
  lsumH += __shfl_xor(lsumH, 16);
  lsumH += __shfl_xor(lsumH, 32);

  // ---- merge the two S-halves (wave qs with wave qs+2) via LDS
  __syncthreads(); // all KV reads done; Vsub reusable as merge scratch
  float* mrgO = (float*)&Vsub[0][0][0];   // [qsw][set][et][lane][4] = 4096 f32
  float* mrgML = mrgO + 4096;             // [qsw][set][{m,l}][lane] = 512 f32

  if (wid >= 2) {
    const int qsw = wid - 2;
#pragma unroll
    for (int et = 0; et < 4; ++et) {
      *reinterpret_cast<f32x4*>(&mrgO[(((qsw * 2 + 0) * 4 + et) * 64 + lane) * 4]) = oaccL[et];
      *reinterpret_cast<f32x4*>(&mrgO[(((qsw * 2 + 1) * 4 + et) * 64 + lane) * 4]) = oaccH[et];
    }
    mrgML[((qsw * 2 + 0) * 2 + 0) * 64 + lane] = mL;
    mrgML[((qsw * 2 + 0) * 2 + 1) * 64 + lane] = lsumL;
    mrgML[((qsw * 2 + 1) * 2 + 0) * 64 + lane] = mH;
    mrgML[((qsw * 2 + 1) * 2 + 1) * 64 + lane] = lsumH;
  }
  __syncthreads();
  if (wid < 2) {
    const int qsw = qs; // == wid
#pragma unroll
    for (int set = 0; set < 2; ++set) {
      float ms = set ? mH : mL;
      float ls = set ? lsumH : lsumL;
      float m1 = mrgML[((qsw * 2 + set) * 2 + 0) * 64 + lane];
      float l1 = mrgML[((qsw * 2 + set) * 2 + 1) * 64 + lane];
      float M = fmaxf(ms, m1);
      float f0 = __builtin_amdgcn_exp2f(ms - M);
      float f1 = __builtin_amdgcn_exp2f(m1 - M);
      float inv = 1.0f / (ls * f0 + l1 * f1);
      const size_t qrow = set ? qrow1 : qrow0;
#pragma unroll
      for (int et = 0; et < 4; ++et) {
        f32x4 O0 = set ? oaccH[et] : oaccL[et];
        f32x4 O1 = *reinterpret_cast<const f32x4*>(
            &mrgO[(((qsw * 2 + set) * 4 + et) * 64 + lane) * 4]);
#pragma unroll
        for (int r = 0; r < 4; ++r) {
          int e = et * 16 + 4 * g + r;
          float val = (O0[r] * f0 + O1[r] * f1) * inv;
          if constexpr (OUT_F32) outF[qrow + e] = val;
          else outB[qrow + e] = f2bf(val * SCALE2); // pre-scale for step-2 Q
        }
      }
    }
  }
}

extern "C" void kernel_launch(void* const* d_in, const int* in_sizes, int n_in,
                              void* d_out, int out_size, void* d_ws, size_t ws_size,
                              hipStream_t stream) {
  const float* R = (const float*)d_in[0];
  const float* Y = (const float*)d_in[1];
  float* outF = (float*)d_out;

  constexpr int NE = B_ * L_ * DM_; // 2,097,152 elements per tensor
  ushort* Rb = (ushort*)d_ws;
  ushort* Yb = Rb + NE;
  ushort* q1 = Yb + NE;

  const int n4 = NE / 4;
  cvt_kernel<<<dim3((n4 + 255) / 256), 256, 0, stream>>>(R, Rb, n4, SCALE2);
  cvt_kernel<<<dim3((n4 + 255) / 256), 256, 0, stream>>>(Y, Yb, n4, 1.0f);

  const int ngrid = B_ * H_ * (L_ / 64); // 512 workgroups
  attn_kernel<false><<<dim3(ngrid), 256, 0, stream>>>(Rb, Yb, nullptr, q1);
  attn_kernel<true><<<dim3(ngrid), 256, 0, stream>>>(q1, Yb, outF, nullptr);
}